// Round 17
// baseline (125.632 us; speedup 1.0000x reference)
//
#include <hip/hip_runtime.h>
#include <hip/hip_fp16.h>

// Criterion_BiNet — adjoint multi-scale dice. R17 = R16 with (1) dot0 cw-gather
// hoisted (w4 loop-invariant -> cw4[6] in regs), (2) all three block types
// INTERLEAVED in one kernel (23-block groups: 6 dot0 + 2 mono + 15 scale) so
// BW-bound and VALU-bound blocks co-reside on CUs.
// K1 hpool_tbl: H-box^4 (5 scales, u8, contiguous layout) + u2f tbl.
// K2 wd_mix: 7360 = 320 grp * (6 dot0 | 2 mono | 15 scale dual-row half2).
// K3 fin_pre + K4 finalize.
// u8 layout: (g,sc,b,h,d,w) at (g*5+sc)*VOL_N + b*DHW + h*DW + d*DIMW + w.
// Slots: [0..35] inter (pair*6+s), [36..71] sum_p, [72..89] sum_t, [90] mono.

#define DIMB 4
#define DIMD 28
#define DIMH 160
#define DIMW 160
#define HW   (DIMH * DIMW)
#define DHW  (DIMD * HW)
#define VOL_N (DIMB * DHW)      // 2,867,200
#define DW   (DIMD * DIMW)      // 4480: h-row stride in u8 layout
#define PGRID 640
#define NSLOTS 91
#define DICE_EPS 1e-7
#define TBL_OFF (480 * 1024)

__device__ __forceinline__ float u2f(int pos, int k, int L) {
    if (k == 1) return 1.f;
    int r = k >> 1;
    float s = 0.f;
    for (int j = max(pos - r, 0); j <= min(pos + r, L - 1); ++j)
        s += (float)(min(j + r, L - 1) - max(j - r, 0) + 1);
    return s / (float)(k * k);
}

__device__ __forceinline__ float wave_sum(float v) {
#pragma unroll
    for (int o = 1; o < 64; o <<= 1) v += __shfl_xor(v, o, 64);
    return v;
}

__device__ __forceinline__ __half2 shfl_h2(__half2 v, int src) {
    int x = __shfl(*reinterpret_cast<int*>(&v), src, 64);
    return *reinterpret_cast<__half2*>(&x);
}

// ---------------- K1: H-axis box^4 (all 5 scales from one raw load) --------
template<int K>
__device__ __forceinline__ void hstore(const float (&raw)[40],
                                       unsigned char* __restrict__ ob,
                                       int l, int c, int wl, int h0)
{
    constexpr int R = K / 2;
    constexpr float INVK = 1.f / (float)K;
    float ox[40];
#pragma unroll
    for (int i = 0; i < 40; ++i) ox[i] = raw[i];
#pragma unroll
    for (int pass = 0; pass < 4; ++pass) {
        float lo[R], hi[R];
#pragma unroll
        for (int i = 0; i < R; ++i) {
            float a = __shfl(ox[40 - R + i], l - 16, 64);
            lo[i] = (c == 0) ? 0.f : a;
            float b = __shfl(ox[i], l + 16, 64);
            hi[i] = (c == 3) ? 0.f : b;
        }
#define HWIN(j) ((j) < R ? lo[(j)] : ((j) < R + 40 ? ox[(j) - R] : hi[(j) - R - 40]))
        float out[40];
        float s = 0.f;
#pragma unroll
        for (int j = 0; j <= 2 * R; ++j) s += HWIN(j);
        out[0] = s * INVK;
#pragma unroll
        for (int i = 1; i < 40; ++i) {
            s += HWIN(i + 2 * R) - HWIN(i - 1);
            out[i] = s * INVK;
        }
#undef HWIN
#pragma unroll
        for (int i = 0; i < 40; ++i) ox[i] = out[i];
    }
#pragma unroll
    for (int i = 0; i < 40; ++i)
        ob[(h0 + i) * DW + wl] = (unsigned char)__float2uint_rn(ox[i] * 255.f);
}

__global__ __launch_bounds__(256) void hpool_tbl(const float* __restrict__ g0,
    const float* __restrict__ g1, const float* __restrict__ g2,
    unsigned char* __restrict__ bufs, float* __restrict__ tbl)
{
    int bx = blockIdx.x;
    int t = threadIdx.x;
    if (bx < 840) {
        int u = bx * 2 + (t >> 7);
        int tt = t & 127;
        int g = u / 560, r = u - g * 560;
        int bd = r / 5, wt = r - bd * 5;
        int b = bd / DIMD, d = bd - b * DIMD;
        const float* in = (g == 0) ? g0 : (g == 1) ? g1 : g2;
        int l = tt & 63, v = tt >> 6;
        int c = l >> 4, wl = v * 16 + (l & 15), h0 = c * 40;
        const float* base = in + (size_t)bd * HW + wt * 32;
        float raw[40];
#pragma unroll
        for (int i = 0; i < 40; ++i) raw[i] = base[(h0 + i) * DIMW + wl];
        unsigned char* ob = bufs + (size_t)(g * 5) * VOL_N + (size_t)b * DHW
                          + d * DIMW + wt * 32;
        hstore<5> (raw, ob + 0 * (size_t)VOL_N, l, c, wl, h0);
        hstore<13>(raw, ob + 1 * (size_t)VOL_N, l, c, wl, h0);
        hstore<23>(raw, ob + 2 * (size_t)VOL_N, l, c, wl, h0);
        hstore<31>(raw, ob + 3 * (size_t)VOL_N, l, c, wl, h0);
        hstore<41>(raw, ob + 4 * (size_t)VOL_N, l, c, wl, h0);
    } else {
        const int KDa[6] = {1, 1, 3, 5, 7, 9};
        const int KHa[6] = {1, 5, 13, 23, 31, 41};
        for (int e = t; e < 1128; e += 256) {
            if (e < 960) tbl[e] = u2f(e % 160, KHa[e / 160], DIMH);
            else {
                int q = e - 960;
                tbl[e] = u2f(q % 28, KDa[q / 28], DIMD);
            }
        }
    }
}

// ---------------- scale building block (dual-row packed half2) -------------
template<int K, int KD>
__device__ __forceinline__ void wd_scale_pk(const unsigned char* __restrict__ tbA,
    const float4* __restrict__ c4, const float4* __restrict__ p4, int base4,
    unsigned int (*S)[164], float (*redS)[4], int t, int l, int wid, int rr,
    int c, bool act, double* __restrict__ partials, int slot_c, int slot_p,
    int bhA)
{
    constexpr int R = K / 2;
    const __half2 INVK2 = __float2half2_rn(1.f / (float)K);
    const __half2 Z2 = __float2half2_rn(0.f);
    __half2 ox[20];
    if (act) {
        unsigned int uA[5], uB[5];
#pragma unroll
        for (int q = 0; q < 5; ++q) {
            uA[q] = *(const unsigned int*)(tbA + 4 * q);
            uB[q] = *(const unsigned int*)(tbA + DW + 4 * q);   // row h+1
        }
#pragma unroll
        for (int q = 0; q < 5; ++q) {
#pragma unroll
            for (int j = 0; j < 4; ++j) {
                float fA = (float)((uA[q] >> (8 * j)) & 0xFFu);
                float fB = (float)((uB[q] >> (8 * j)) & 0xFFu);
                ox[4 * q + j] = __floats2half2_rn(fA, fB);
            }
        }
    } else {
#pragma unroll
        for (int i = 0; i < 20; ++i) ox[i] = Z2;
    }
#pragma unroll
    for (int pass = 0; pass < 4; ++pass) {
        __half2 lo[R], hi[R];
#pragma unroll
        for (int i = 0; i < R; ++i) {
            __half2 a = shfl_h2(ox[20 - R + i], l - 1);
            lo[i] = (c == 0) ? Z2 : a;
            __half2 b = shfl_h2(ox[i], l + 1);
            hi[i] = (c == 7) ? Z2 : b;
        }
#define WWIN(j) ((j) < R ? lo[(j)] : ((j) < R + 20 ? ox[(j) - R] : hi[(j) - R - 20]))
        __half2 out[20];
        __half2 s = Z2;
#pragma unroll
        for (int j = 0; j <= 2 * R; ++j) s = __hadd2(s, WWIN(j));
        out[0] = __hmul2(s, INVK2);
#pragma unroll
        for (int i = 1; i < 20; ++i) {
            s = __hadd2(s, __hsub2(WWIN(i + 2 * R), WWIN(i - 1)));
            out[i] = __hmul2(s, INVK2);
        }
#undef WWIN
#pragma unroll
        for (int i = 0; i < 20; ++i) ox[i] = out[i];
    }
    if (act) {
#pragma unroll
        for (int i = 0; i < 20; ++i)
            S[rr][c * 20 + i] = *reinterpret_cast<unsigned int*>(&ox[i]);
    }
    __syncthreads();
    if constexpr (KD > 1) {
        constexpr int RD = KD / 2;
        const __half2 INVKD2 = __float2half2_rn(1.f / (float)KD);
        if (t < DIMW) {
            __half2 x[28];
#pragma unroll
            for (int j = 0; j < 28; ++j)
                x[j] = *reinterpret_cast<const __half2*>(&S[j][t]);
#pragma unroll
            for (int p = 0; p < 4; ++p) {
                __half2 y[28];
                __half2 s = Z2;
#pragma unroll
                for (int j = 0; j <= RD; ++j) s = __hadd2(s, x[j]);
                y[0] = s;
#pragma unroll
                for (int i = 1; i < 28; ++i) {
                    if (i + RD < 28) s = __hadd2(s, x[i + RD]);
                    if (i - RD - 1 >= 0) s = __hsub2(s, x[i - RD - 1]);
                    y[i] = s;
                }
#pragma unroll
                for (int i = 0; i < 28; ++i) x[i] = __hmul2(y[i], INVKD2);
            }
#pragma unroll
            for (int j = 0; j < 28; ++j)
                S[j][t] = *reinterpret_cast<unsigned int*>(&x[j]);
        }
        __syncthreads();
    }
    float aicA = 0.f, aipA = 0.f, aicB = 0.f, aipB = 0.f;
    for (int e4 = t; e4 < 1120; e4 += 256) {
        int dd = e4 / 40, w4 = e4 - dd * 40;
        int fi = base4 + dd * (HW / 4) + w4;
        float4 vcA = c4[fi],      vpA = p4[fi];
        float4 vcB = c4[fi + 40], vpB = p4[fi + 40];
        const uint4 sv = *(const uint4*)&S[dd][4 * w4];
        float2 s0 = __half22float2(*reinterpret_cast<const __half2*>(&sv.x));
        float2 s1 = __half22float2(*reinterpret_cast<const __half2*>(&sv.y));
        float2 s2 = __half22float2(*reinterpret_cast<const __half2*>(&sv.z));
        float2 s3 = __half22float2(*reinterpret_cast<const __half2*>(&sv.w));
        aicA += vcA.x*s0.x + vcA.y*s1.x + vcA.z*s2.x + vcA.w*s3.x;
        aipA += vpA.x*s0.x + vpA.y*s1.x + vpA.z*s2.x + vpA.w*s3.x;
        aicB += vcB.x*s0.y + vcB.y*s1.y + vcB.z*s2.y + vcB.w*s3.y;
        aipB += vpB.x*s0.y + vpB.y*s1.y + vpB.z*s2.y + vpB.w*s3.y;
    }
    const float SC = 1.f / 255.f;
    float v0 = wave_sum(aicA) * SC, v1 = wave_sum(aipA) * SC;
    float v2 = wave_sum(aicB) * SC, v3 = wave_sum(aipB) * SC;
    if (l == 0) {
        redS[wid][0] = v0; redS[wid][1] = v1;
        redS[wid][2] = v2; redS[wid][3] = v3;
    }
    __syncthreads();
    if (t < 4) {
        double rv = (double)redS[0][t] + redS[1][t] + redS[2][t] + redS[3][t];
        int slot = (t & 1) ? slot_p : slot_c;
        int bh = bhA + (t >> 1);
        partials[(size_t)slot * PGRID + bh] = rv;
    }
}

// ---------------- K2: interleaved dot0 | mono | scale ----------------
__global__ __launch_bounds__(256) void wd_mix(const unsigned char* __restrict__ bufs,
    const float* __restrict__ pc0, const float* __restrict__ pp0,
    const float* __restrict__ pc1, const float* __restrict__ pp1,
    const float* __restrict__ pc2, const float* __restrict__ pp2,
    const float* __restrict__ tr0, const float* __restrict__ tr1,
    const float* __restrict__ tr2, const float* __restrict__ o6,
    const float* __restrict__ tbl, double* __restrict__ partials)
{
    __shared__ __align__(16) unsigned int S[DIMD][164];
    __shared__ float redS[4][24];
    int bx0 = blockIdx.x;                 // 7360 = 320 grp * 23
    int t = threadIdx.x;
    int grp = bx0 / 23, pos = bx0 - grp * 23;

    if (pos < 6) {
        // dot0 + 18 weighted sums; w4 loop-invariant -> cw4 in regs
        int did = grp * 6 + pos;          // 1920 = 3g * 640
        int g = did / PGRID, blk = did - g * PGRID;
        const float* pc = (g == 0) ? pc0 : (g == 1) ? pc1 : pc2;
        const float* pp = (g == 0) ? pp0 : (g == 1) ? pp1 : pp2;
        const float* tr = (g == 0) ? tr0 : (g == 1) ? tr1 : tr2;
        const float4* c4p = (const float4*)pc;
        const float4* p4p = (const float4*)pp;
        const float4* t4p = (const float4*)tr;
        const int N4 = VOL_N / 4;
        int i0 = blk * 256 + t;
        int w4 = i0 % 40;                 // stride 163840 % 40 == 0
        float4 cw4[6];
#pragma unroll
        for (int s = 0; s < 6; ++s)
            cw4[s] = *(const float4*)(tbl + s * 160 + 4 * w4);
        float vals[20];
#pragma unroll
        for (int i = 0; i < 20; ++i) vals[i] = 0.f;
        for (int i4 = i0; i4 < N4; i4 += PGRID * 256) {
            int rest = i4 / 40;
            int h = rest % DIMH;
            int d = (rest / DIMH) % DIMD;
            float4 vc = c4p[i4], vp = p4p[i4], vt = t4p[i4];
            vals[0] += vc.x*vt.x + vc.y*vt.y + vc.z*vt.z + vc.w*vt.w;
            vals[1] += vp.x*vt.x + vp.y*vt.y + vp.z*vt.z + vp.w*vt.w;
#pragma unroll
            for (int s = 0; s < 6; ++s) {
                float cdh = tbl[960 + s * 28 + d] * tbl[s * 160 + h];
                vals[2 + s]  += cdh * (cw4[s].x*vc.x + cw4[s].y*vc.y + cw4[s].z*vc.z + cw4[s].w*vc.w);
                vals[8 + s]  += cdh * (cw4[s].x*vp.x + cw4[s].y*vp.y + cw4[s].z*vp.z + cw4[s].w*vp.w);
                vals[14 + s] += cdh * (cw4[s].x*vt.x + cw4[s].y*vt.y + cw4[s].z*vt.z + cw4[s].w*vt.w);
            }
        }
        int lane = t & 63, wid = t >> 6;
#pragma unroll
        for (int i = 0; i < 20; ++i) {
            float rv = wave_sum(vals[i]);
            if (lane == 0) redS[wid][i] = rv;
        }
        __syncthreads();
        if (t < 20) {
            double rv = (double)redS[0][t] + redS[1][t] + redS[2][t] + redS[3][t];
            int slot;
            if (t == 0) slot = (2 * g) * 6;
            else if (t == 1) slot = (2 * g + 1) * 6;
            else {
                int i = t - 2, vv = i / 6, s = i % 6;
                slot = (vv == 0) ? 36 + (2 * g) * 6 + s
                     : (vv == 1) ? 36 + (2 * g + 1) * 6 + s
                                 : 72 + g * 6 + s;
            }
            partials[(size_t)slot * PGRID + blk] = rv;
        }
        return;
    }

    if (pos < 8) {
        // mono
        int mb = grp * 2 + (pos - 6);     // 640
        const int N4 = VOL_N / 4, PB = N4 / DIMB;
        float acc = 0.f;
        const float4* p = (const float4*)o6;
        for (int i = mb * 256 + t; i < N4; i += PGRID * 256) {
            int b = i / PB, r4 = i - b * PB;
            size_t a = (size_t)(b * 6) * PB + r4;
            float4 prev = p[a];
#pragma unroll
            for (int cc = 1; cc < 6; ++cc) {
                float4 cur = p[a + (size_t)cc * PB];
                acc += fmaxf(prev.x - cur.x, 0.f) + fmaxf(prev.y - cur.y, 0.f)
                     + fmaxf(prev.z - cur.z, 0.f) + fmaxf(prev.w - cur.w, 0.f);
                prev = cur;
            }
        }
        float rv = wave_sum(acc * 2.f);
        int lane = t & 63, wid = t >> 6;
        if (lane == 0) redS[wid][0] = rv;
        __syncthreads();
        if (t == 0)
            partials[(size_t)90 * PGRID + mb] =
                (double)redS[0][0] + redS[1][0] + redS[2][0] + redS[3][0];
        return;
    }

    // scale blocks: sid in [0,4800); unit's 5 scales are consecutive sids
    int sid = grp * 15 + (pos - 8);
    int u = sid / 5, q = sid - u * 5;     // q: 0=k41..4=k5
    int g = u / 320, pj = u - g * 320;
    int bhA = 2 * pj;
    int b = bhA / DIMH, h = bhA - b * DIMH;
    const float* pc = (g == 0) ? pc0 : (g == 1) ? pc1 : pc2;
    const float* pp = (g == 0) ? pp0 : (g == 1) ? pp1 : pp2;
    int base4 = b * (DHW / 4) + h * 40;
    const float4* c4 = (const float4*)pc;
    const float4* p4 = (const float4*)pp;
    int l = t & 63, wid = t >> 6;
    int rr = wid * 7 + (l >> 3), c = l & 7;
    bool act = (l < 56);
    int sbuf = 4 - q;                      // k41,k31,k23,k13,k5
    const unsigned char* tbA = bufs + (size_t)(g * 5 + sbuf) * VOL_N
                             + (size_t)b * DHW + (size_t)h * DW
                             + rr * DIMW + c * 20;
    int s = 5 - q;
    int slot_c = (2 * g) * 6 + s, slot_p = (2 * g + 1) * 6 + s;
    switch (q) {
        case 0: wd_scale_pk<41, 9>(tbA, c4, p4, base4, S, (float(*)[4])&redS[0][0], t, l, wid, rr, c, act, partials, slot_c, slot_p, bhA); break;
        case 1: wd_scale_pk<31, 7>(tbA, c4, p4, base4, S, (float(*)[4])&redS[0][0], t, l, wid, rr, c, act, partials, slot_c, slot_p, bhA); break;
        case 2: wd_scale_pk<23, 5>(tbA, c4, p4, base4, S, (float(*)[4])&redS[0][0], t, l, wid, rr, c, act, partials, slot_c, slot_p, bhA); break;
        case 3: wd_scale_pk<13, 3>(tbA, c4, p4, base4, S, (float(*)[4])&redS[0][0], t, l, wid, rr, c, act, partials, slot_c, slot_p, bhA); break;
        default: wd_scale_pk<5, 1>(tbA, c4, p4, base4, S, (float(*)[4])&redS[0][0], t, l, wid, rr, c, act, partials, slot_c, slot_p, bhA); break;
    }
}

// ---------------- K3/K4: reduction tail ----------------
__global__ __launch_bounds__(64) void fin_pre(const double* __restrict__ partials,
                                              double* __restrict__ ssum)
{
    int slot = blockIdx.x, t = threadIdx.x;
    double a = 0.0;
    for (int i = t; i < PGRID; i += 64) a += partials[(size_t)slot * PGRID + i];
#pragma unroll
    for (int o = 1; o < 64; o <<= 1) a += __shfl_xor(a, o, 64);
    if (t == 0) ssum[slot] = a;
}

__global__ void finalize(const double* __restrict__ ssum,
                         const float* __restrict__ off_a,
                         const float* __restrict__ off_b,
                         const float* __restrict__ off_ta,
                         const float* __restrict__ off_tb,
                         float* __restrict__ out)
{
    if (threadIdx.x == 0) {
        double loss = 0.0;
        for (int pair = 0; pair < 6; ++pair) {
            for (int s = 0; s < 6; ++s) {
                double inter = ssum[pair * 6 + s];
                double sp = ssum[36 + pair * 6 + s];
                double st = ssum[72 + (pair / 2) * 6 + s];
                loss += 0.2 * (1.0 - 2.0 * inter / (sp + st + DICE_EPS)) / 6.0;
            }
        }
        loss += 0.1 * (ssum[90] / (double)VOL_N);
        double oa = 0.0, ob = 0.0;
        for (int i = 0; i < 12; ++i) {
            oa += fabs((double)off_a[i] - (double)off_ta[i]);
            ob += fabs((double)off_b[i] - (double)off_tb[i]);
        }
        loss += 0.1 * (oa / 12.0) + 0.1 * (ob / 12.0);
        out[0] = (float)loss;
    }
}

extern "C" void kernel_launch(void* const* d_in, const int* in_sizes, int n_in,
                              void* d_out, int out_size, void* d_ws, size_t ws_size,
                              hipStream_t stream)
{
    double* partials = (double*)d_ws;                   // 91*640*8 = 465,920 B
    double* ssum = partials + (size_t)NSLOTS * PGRID;   // +91*8 < 480 KB
    float* tbl = (float*)((char*)d_ws + TBL_OFF);       // 1128 floats
    unsigned char* bufs = (unsigned char*)d_ws + 512 * 1024;  // 15*VOL_N u8 = 43 MB

    const float* pred[6] = {(const float*)d_in[0], (const float*)d_in[1],
                            (const float*)d_in[3], (const float*)d_in[4],
                            (const float*)d_in[6], (const float*)d_in[7]};
    const float* gt[3] = {(const float*)d_in[2], (const float*)d_in[5],
                          (const float*)d_in[8]};

    hpool_tbl<<<841, 256, 0, stream>>>(gt[0], gt[1], gt[2], bufs, tbl);
    wd_mix<<<7360, 256, 0, stream>>>(bufs, pred[0], pred[1], pred[2], pred[3],
                                     pred[4], pred[5], gt[0], gt[1], gt[2],
                                     (const float*)d_in[9], tbl, partials);
    fin_pre<<<NSLOTS, 64, 0, stream>>>(partials, ssum);
    finalize<<<1, 64, 0, stream>>>(ssum,
                                   (const float*)d_in[10], (const float*)d_in[11],
                                   (const float*)d_in[12], (const float*)d_in[13],
                                   (float*)d_out);
}

// Round 18
// 113.253 us; speedup vs baseline: 1.1093x; 1.1093x over previous
//
#include <hip/hip_runtime.h>
#include <hip/hip_fp16.h>

// Criterion_BiNet — adjoint multi-scale dice. R18 = R17 interleave + XCD
// clustering: bx&7 = XCD, bx>>3 = per-XCD index into 40 groups x 23 blocks
// {6 dot0 | 2 mono | 15 scale}. A unit's 5 scale blocks are consecutive on
// ONE XCD (pred slab + u8 tile L2-served once), while block types still mix
// on every CU (BW-bound dot0/mono overlap VALU-bound scale chains).
// K1 hpool_tbl: H-box^4 (5 scales, u8, contiguous layout) + u2f tbl.
// K2 wd_mix: 7360 = 8 XCD * 920.  K3 fin_pre + K4 finalize.
// u8 layout: (g,sc,b,h,d,w) at (g*5+sc)*VOL_N + b*DHW + h*DW + d*DIMW + w.
// Slots: [0..35] inter (pair*6+s), [36..71] sum_p, [72..89] sum_t, [90] mono.

#define DIMB 4
#define DIMD 28
#define DIMH 160
#define DIMW 160
#define HW   (DIMH * DIMW)
#define DHW  (DIMD * HW)
#define VOL_N (DIMB * DHW)      // 2,867,200
#define DW   (DIMD * DIMW)      // 4480: h-row stride in u8 layout
#define PGRID 640
#define NSLOTS 91
#define DICE_EPS 1e-7
#define TBL_OFF (480 * 1024)

__device__ __forceinline__ float u2f(int pos, int k, int L) {
    if (k == 1) return 1.f;
    int r = k >> 1;
    float s = 0.f;
    for (int j = max(pos - r, 0); j <= min(pos + r, L - 1); ++j)
        s += (float)(min(j + r, L - 1) - max(j - r, 0) + 1);
    return s / (float)(k * k);
}

__device__ __forceinline__ float wave_sum(float v) {
#pragma unroll
    for (int o = 1; o < 64; o <<= 1) v += __shfl_xor(v, o, 64);
    return v;
}

__device__ __forceinline__ __half2 shfl_h2(__half2 v, int src) {
    int x = __shfl(*reinterpret_cast<int*>(&v), src, 64);
    return *reinterpret_cast<__half2*>(&x);
}

// ---------------- K1: H-axis box^4 (all 5 scales from one raw load) --------
template<int K>
__device__ __forceinline__ void hstore(const float (&raw)[40],
                                       unsigned char* __restrict__ ob,
                                       int l, int c, int wl, int h0)
{
    constexpr int R = K / 2;
    constexpr float INVK = 1.f / (float)K;
    float ox[40];
#pragma unroll
    for (int i = 0; i < 40; ++i) ox[i] = raw[i];
#pragma unroll
    for (int pass = 0; pass < 4; ++pass) {
        float lo[R], hi[R];
#pragma unroll
        for (int i = 0; i < R; ++i) {
            float a = __shfl(ox[40 - R + i], l - 16, 64);
            lo[i] = (c == 0) ? 0.f : a;
            float b = __shfl(ox[i], l + 16, 64);
            hi[i] = (c == 3) ? 0.f : b;
        }
#define HWIN(j) ((j) < R ? lo[(j)] : ((j) < R + 40 ? ox[(j) - R] : hi[(j) - R - 40]))
        float out[40];
        float s = 0.f;
#pragma unroll
        for (int j = 0; j <= 2 * R; ++j) s += HWIN(j);
        out[0] = s * INVK;
#pragma unroll
        for (int i = 1; i < 40; ++i) {
            s += HWIN(i + 2 * R) - HWIN(i - 1);
            out[i] = s * INVK;
        }
#undef HWIN
#pragma unroll
        for (int i = 0; i < 40; ++i) ox[i] = out[i];
    }
#pragma unroll
    for (int i = 0; i < 40; ++i)
        ob[(h0 + i) * DW + wl] = (unsigned char)__float2uint_rn(ox[i] * 255.f);
}

__global__ __launch_bounds__(256) void hpool_tbl(const float* __restrict__ g0,
    const float* __restrict__ g1, const float* __restrict__ g2,
    unsigned char* __restrict__ bufs, float* __restrict__ tbl)
{
    int bx = blockIdx.x;
    int t = threadIdx.x;
    if (bx < 840) {
        int u = bx * 2 + (t >> 7);
        int tt = t & 127;
        int g = u / 560, r = u - g * 560;
        int bd = r / 5, wt = r - bd * 5;
        int b = bd / DIMD, d = bd - b * DIMD;
        const float* in = (g == 0) ? g0 : (g == 1) ? g1 : g2;
        int l = tt & 63, v = tt >> 6;
        int c = l >> 4, wl = v * 16 + (l & 15), h0 = c * 40;
        const float* base = in + (size_t)bd * HW + wt * 32;
        float raw[40];
#pragma unroll
        for (int i = 0; i < 40; ++i) raw[i] = base[(h0 + i) * DIMW + wl];
        unsigned char* ob = bufs + (size_t)(g * 5) * VOL_N + (size_t)b * DHW
                          + d * DIMW + wt * 32;
        hstore<5> (raw, ob + 0 * (size_t)VOL_N, l, c, wl, h0);
        hstore<13>(raw, ob + 1 * (size_t)VOL_N, l, c, wl, h0);
        hstore<23>(raw, ob + 2 * (size_t)VOL_N, l, c, wl, h0);
        hstore<31>(raw, ob + 3 * (size_t)VOL_N, l, c, wl, h0);
        hstore<41>(raw, ob + 4 * (size_t)VOL_N, l, c, wl, h0);
    } else {
        const int KDa[6] = {1, 1, 3, 5, 7, 9};
        const int KHa[6] = {1, 5, 13, 23, 31, 41};
        for (int e = t; e < 1128; e += 256) {
            if (e < 960) tbl[e] = u2f(e % 160, KHa[e / 160], DIMH);
            else {
                int q = e - 960;
                tbl[e] = u2f(q % 28, KDa[q / 28], DIMD);
            }
        }
    }
}

// ---------------- scale building block (dual-row packed half2) -------------
template<int K, int KD>
__device__ __forceinline__ void wd_scale_pk(const unsigned char* __restrict__ tbA,
    const float4* __restrict__ c4, const float4* __restrict__ p4, int base4,
    unsigned int (*S)[164], float (*redS)[4], int t, int l, int wid, int rr,
    int c, bool act, double* __restrict__ partials, int slot_c, int slot_p,
    int bhA)
{
    constexpr int R = K / 2;
    const __half2 INVK2 = __float2half2_rn(1.f / (float)K);
    const __half2 Z2 = __float2half2_rn(0.f);
    __half2 ox[20];
    if (act) {
        unsigned int uA[5], uB[5];
#pragma unroll
        for (int q = 0; q < 5; ++q) {
            uA[q] = *(const unsigned int*)(tbA + 4 * q);
            uB[q] = *(const unsigned int*)(tbA + DW + 4 * q);   // row h+1
        }
#pragma unroll
        for (int q = 0; q < 5; ++q) {
#pragma unroll
            for (int j = 0; j < 4; ++j) {
                float fA = (float)((uA[q] >> (8 * j)) & 0xFFu);
                float fB = (float)((uB[q] >> (8 * j)) & 0xFFu);
                ox[4 * q + j] = __floats2half2_rn(fA, fB);
            }
        }
    } else {
#pragma unroll
        for (int i = 0; i < 20; ++i) ox[i] = Z2;
    }
#pragma unroll
    for (int pass = 0; pass < 4; ++pass) {
        __half2 lo[R], hi[R];
#pragma unroll
        for (int i = 0; i < R; ++i) {
            __half2 a = shfl_h2(ox[20 - R + i], l - 1);
            lo[i] = (c == 0) ? Z2 : a;
            __half2 b = shfl_h2(ox[i], l + 1);
            hi[i] = (c == 7) ? Z2 : b;
        }
#define WWIN(j) ((j) < R ? lo[(j)] : ((j) < R + 20 ? ox[(j) - R] : hi[(j) - R - 20]))
        __half2 out[20];
        __half2 s = Z2;
#pragma unroll
        for (int j = 0; j <= 2 * R; ++j) s = __hadd2(s, WWIN(j));
        out[0] = __hmul2(s, INVK2);
#pragma unroll
        for (int i = 1; i < 20; ++i) {
            s = __hadd2(s, __hsub2(WWIN(i + 2 * R), WWIN(i - 1)));
            out[i] = __hmul2(s, INVK2);
        }
#undef WWIN
#pragma unroll
        for (int i = 0; i < 20; ++i) ox[i] = out[i];
    }
    if (act) {
#pragma unroll
        for (int i = 0; i < 20; ++i)
            S[rr][c * 20 + i] = *reinterpret_cast<unsigned int*>(&ox[i]);
    }
    __syncthreads();
    if constexpr (KD > 1) {
        constexpr int RD = KD / 2;
        const __half2 INVKD2 = __float2half2_rn(1.f / (float)KD);
        if (t < DIMW) {
            __half2 x[28];
#pragma unroll
            for (int j = 0; j < 28; ++j)
                x[j] = *reinterpret_cast<const __half2*>(&S[j][t]);
#pragma unroll
            for (int p = 0; p < 4; ++p) {
                __half2 y[28];
                __half2 s = Z2;
#pragma unroll
                for (int j = 0; j <= RD; ++j) s = __hadd2(s, x[j]);
                y[0] = s;
#pragma unroll
                for (int i = 1; i < 28; ++i) {
                    if (i + RD < 28) s = __hadd2(s, x[i + RD]);
                    if (i - RD - 1 >= 0) s = __hsub2(s, x[i - RD - 1]);
                    y[i] = s;
                }
#pragma unroll
                for (int i = 0; i < 28; ++i) x[i] = __hmul2(y[i], INVKD2);
            }
#pragma unroll
            for (int j = 0; j < 28; ++j)
                S[j][t] = *reinterpret_cast<unsigned int*>(&x[j]);
        }
        __syncthreads();
    }
    float aicA = 0.f, aipA = 0.f, aicB = 0.f, aipB = 0.f;
    for (int e4 = t; e4 < 1120; e4 += 256) {
        int dd = e4 / 40, w4 = e4 - dd * 40;
        int fi = base4 + dd * (HW / 4) + w4;
        float4 vcA = c4[fi],      vpA = p4[fi];
        float4 vcB = c4[fi + 40], vpB = p4[fi + 40];
        const uint4 sv = *(const uint4*)&S[dd][4 * w4];
        float2 s0 = __half22float2(*reinterpret_cast<const __half2*>(&sv.x));
        float2 s1 = __half22float2(*reinterpret_cast<const __half2*>(&sv.y));
        float2 s2 = __half22float2(*reinterpret_cast<const __half2*>(&sv.z));
        float2 s3 = __half22float2(*reinterpret_cast<const __half2*>(&sv.w));
        aicA += vcA.x*s0.x + vcA.y*s1.x + vcA.z*s2.x + vcA.w*s3.x;
        aipA += vpA.x*s0.x + vpA.y*s1.x + vpA.z*s2.x + vpA.w*s3.x;
        aicB += vcB.x*s0.y + vcB.y*s1.y + vcB.z*s2.y + vcB.w*s3.y;
        aipB += vpB.x*s0.y + vpB.y*s1.y + vpB.z*s2.y + vpB.w*s3.y;
    }
    const float SC = 1.f / 255.f;
    float v0 = wave_sum(aicA) * SC, v1 = wave_sum(aipA) * SC;
    float v2 = wave_sum(aicB) * SC, v3 = wave_sum(aipB) * SC;
    if (l == 0) {
        redS[wid][0] = v0; redS[wid][1] = v1;
        redS[wid][2] = v2; redS[wid][3] = v3;
    }
    __syncthreads();
    if (t < 4) {
        double rv = (double)redS[0][t] + redS[1][t] + redS[2][t] + redS[3][t];
        int slot = (t & 1) ? slot_p : slot_c;
        int bh = bhA + (t >> 1);
        partials[(size_t)slot * PGRID + bh] = rv;
    }
}

// ---------------- K2: XCD-clustered interleaved dot0 | mono | scale --------
__global__ __launch_bounds__(256) void wd_mix(const unsigned char* __restrict__ bufs,
    const float* __restrict__ pc0, const float* __restrict__ pp0,
    const float* __restrict__ pc1, const float* __restrict__ pp1,
    const float* __restrict__ pc2, const float* __restrict__ pp2,
    const float* __restrict__ tr0, const float* __restrict__ tr1,
    const float* __restrict__ tr2, const float* __restrict__ o6,
    const float* __restrict__ tbl, double* __restrict__ partials)
{
    __shared__ __align__(16) unsigned int S[DIMD][164];
    __shared__ float redS[4][24];
    int bx0 = blockIdx.x;                 // 7360 = 8 XCD * 920
    int t = threadIdx.x;
    int x = bx0 & 7;                      // XCD id (dispatch round-robin)
    int j = bx0 >> 3;                     // per-XCD index [0,920)
    int grp = j / 23, pos = j - grp * 23; // 40 groups x 23

    if (pos < 6) {
        // dot0 + 18 weighted sums; w4 loop-invariant -> cw4 in regs
        int did = x * 240 + grp * 6 + pos;    // [0,1920)
        int g = did / PGRID, blk = did - g * PGRID;
        const float* pc = (g == 0) ? pc0 : (g == 1) ? pc1 : pc2;
        const float* pp = (g == 0) ? pp0 : (g == 1) ? pp1 : pp2;
        const float* tr = (g == 0) ? tr0 : (g == 1) ? tr1 : tr2;
        const float4* c4p = (const float4*)pc;
        const float4* p4p = (const float4*)pp;
        const float4* t4p = (const float4*)tr;
        const int N4 = VOL_N / 4;
        int i0 = blk * 256 + t;
        int w4 = i0 % 40;                 // stride 163840 % 40 == 0
        float4 cw4[6];
#pragma unroll
        for (int s = 0; s < 6; ++s)
            cw4[s] = *(const float4*)(tbl + s * 160 + 4 * w4);
        float vals[20];
#pragma unroll
        for (int i = 0; i < 20; ++i) vals[i] = 0.f;
        for (int i4 = i0; i4 < N4; i4 += PGRID * 256) {
            int rest = i4 / 40;
            int h = rest % DIMH;
            int d = (rest / DIMH) % DIMD;
            float4 vc = c4p[i4], vp = p4p[i4], vt = t4p[i4];
            vals[0] += vc.x*vt.x + vc.y*vt.y + vc.z*vt.z + vc.w*vt.w;
            vals[1] += vp.x*vt.x + vp.y*vt.y + vp.z*vt.z + vp.w*vt.w;
#pragma unroll
            for (int s = 0; s < 6; ++s) {
                float cdh = tbl[960 + s * 28 + d] * tbl[s * 160 + h];
                vals[2 + s]  += cdh * (cw4[s].x*vc.x + cw4[s].y*vc.y + cw4[s].z*vc.z + cw4[s].w*vc.w);
                vals[8 + s]  += cdh * (cw4[s].x*vp.x + cw4[s].y*vp.y + cw4[s].z*vp.z + cw4[s].w*vp.w);
                vals[14 + s] += cdh * (cw4[s].x*vt.x + cw4[s].y*vt.y + cw4[s].z*vt.z + cw4[s].w*vt.w);
            }
        }
        int lane = t & 63, wid = t >> 6;
#pragma unroll
        for (int i = 0; i < 20; ++i) {
            float rv = wave_sum(vals[i]);
            if (lane == 0) redS[wid][i] = rv;
        }
        __syncthreads();
        if (t < 20) {
            double rv = (double)redS[0][t] + redS[1][t] + redS[2][t] + redS[3][t];
            int slot;
            if (t == 0) slot = (2 * g) * 6;
            else if (t == 1) slot = (2 * g + 1) * 6;
            else {
                int i = t - 2, vv = i / 6, s = i % 6;
                slot = (vv == 0) ? 36 + (2 * g) * 6 + s
                     : (vv == 1) ? 36 + (2 * g + 1) * 6 + s
                                 : 72 + g * 6 + s;
            }
            partials[(size_t)slot * PGRID + blk] = rv;
        }
        return;
    }

    if (pos < 8) {
        // mono
        int mb = x * 80 + grp * 2 + (pos - 6);   // [0,640)
        const int N4 = VOL_N / 4, PB = N4 / DIMB;
        float acc = 0.f;
        const float4* p = (const float4*)o6;
        for (int i = mb * 256 + t; i < N4; i += PGRID * 256) {
            int b = i / PB, r4 = i - b * PB;
            size_t a = (size_t)(b * 6) * PB + r4;
            float4 prev = p[a];
#pragma unroll
            for (int cc = 1; cc < 6; ++cc) {
                float4 cur = p[a + (size_t)cc * PB];
                acc += fmaxf(prev.x - cur.x, 0.f) + fmaxf(prev.y - cur.y, 0.f)
                     + fmaxf(prev.z - cur.z, 0.f) + fmaxf(prev.w - cur.w, 0.f);
                prev = cur;
            }
        }
        float rv = wave_sum(acc * 2.f);
        int lane = t & 63, wid = t >> 6;
        if (lane == 0) redS[wid][0] = rv;
        __syncthreads();
        if (t == 0)
            partials[(size_t)90 * PGRID + mb] =
                (double)redS[0][0] + redS[1][0] + redS[2][0] + redS[3][0];
        return;
    }

    // scale blocks: unit's 5 blocks are consecutive j on THIS XCD
    int sid = x * 600 + grp * 15 + (pos - 8);    // [0,4800)
    int u = sid / 5, q = sid - u * 5;            // q: 0=k41..4=k5
    int g = u / 320, pj = u - g * 320;
    int bhA = 2 * pj;
    int b = bhA / DIMH, h = bhA - b * DIMH;
    const float* pc = (g == 0) ? pc0 : (g == 1) ? pc1 : pc2;
    const float* pp = (g == 0) ? pp0 : (g == 1) ? pp1 : pp2;
    int base4 = b * (DHW / 4) + h * 40;
    const float4* c4 = (const float4*)pc;
    const float4* p4 = (const float4*)pp;
    int l = t & 63, wid = t >> 6;
    int rr = wid * 7 + (l >> 3), c = l & 7;
    bool act = (l < 56);
    int sbuf = 4 - q;                      // k41,k31,k23,k13,k5
    const unsigned char* tbA = bufs + (size_t)(g * 5 + sbuf) * VOL_N
                             + (size_t)b * DHW + (size_t)h * DW
                             + rr * DIMW + c * 20;
    int s = 5 - q;
    int slot_c = (2 * g) * 6 + s, slot_p = (2 * g + 1) * 6 + s;
    switch (q) {
        case 0: wd_scale_pk<41, 9>(tbA, c4, p4, base4, S, (float(*)[4])&redS[0][0], t, l, wid, rr, c, act, partials, slot_c, slot_p, bhA); break;
        case 1: wd_scale_pk<31, 7>(tbA, c4, p4, base4, S, (float(*)[4])&redS[0][0], t, l, wid, rr, c, act, partials, slot_c, slot_p, bhA); break;
        case 2: wd_scale_pk<23, 5>(tbA, c4, p4, base4, S, (float(*)[4])&redS[0][0], t, l, wid, rr, c, act, partials, slot_c, slot_p, bhA); break;
        case 3: wd_scale_pk<13, 3>(tbA, c4, p4, base4, S, (float(*)[4])&redS[0][0], t, l, wid, rr, c, act, partials, slot_c, slot_p, bhA); break;
        default: wd_scale_pk<5, 1>(tbA, c4, p4, base4, S, (float(*)[4])&redS[0][0], t, l, wid, rr, c, act, partials, slot_c, slot_p, bhA); break;
    }
}

// ---------------- K3/K4: reduction tail ----------------
__global__ __launch_bounds__(64) void fin_pre(const double* __restrict__ partials,
                                              double* __restrict__ ssum)
{
    int slot = blockIdx.x, t = threadIdx.x;
    double a = 0.0;
    for (int i = t; i < PGRID; i += 64) a += partials[(size_t)slot * PGRID + i];
#pragma unroll
    for (int o = 1; o < 64; o <<= 1) a += __shfl_xor(a, o, 64);
    if (t == 0) ssum[slot] = a;
}

__global__ void finalize(const double* __restrict__ ssum,
                         const float* __restrict__ off_a,
                         const float* __restrict__ off_b,
                         const float* __restrict__ off_ta,
                         const float* __restrict__ off_tb,
                         float* __restrict__ out)
{
    if (threadIdx.x == 0) {
        double loss = 0.0;
        for (int pair = 0; pair < 6; ++pair) {
            for (int s = 0; s < 6; ++s) {
                double inter = ssum[pair * 6 + s];
                double sp = ssum[36 + pair * 6 + s];
                double st = ssum[72 + (pair / 2) * 6 + s];
                loss += 0.2 * (1.0 - 2.0 * inter / (sp + st + DICE_EPS)) / 6.0;
            }
        }
        loss += 0.1 * (ssum[90] / (double)VOL_N);
        double oa = 0.0, ob = 0.0;
        for (int i = 0; i < 12; ++i) {
            oa += fabs((double)off_a[i] - (double)off_ta[i]);
            ob += fabs((double)off_b[i] - (double)off_tb[i]);
        }
        loss += 0.1 * (oa / 12.0) + 0.1 * (ob / 12.0);
        out[0] = (float)loss;
    }
}

extern "C" void kernel_launch(void* const* d_in, const int* in_sizes, int n_in,
                              void* d_out, int out_size, void* d_ws, size_t ws_size,
                              hipStream_t stream)
{
    double* partials = (double*)d_ws;                   // 91*640*8 = 465,920 B
    double* ssum = partials + (size_t)NSLOTS * PGRID;   // +91*8 < 480 KB
    float* tbl = (float*)((char*)d_ws + TBL_OFF);       // 1128 floats
    unsigned char* bufs = (unsigned char*)d_ws + 512 * 1024;  // 15*VOL_N u8 = 43 MB

    const float* pred[6] = {(const float*)d_in[0], (const float*)d_in[1],
                            (const float*)d_in[3], (const float*)d_in[4],
                            (const float*)d_in[6], (const float*)d_in[7]};
    const float* gt[3] = {(const float*)d_in[2], (const float*)d_in[5],
                          (const float*)d_in[8]};

    hpool_tbl<<<841, 256, 0, stream>>>(gt[0], gt[1], gt[2], bufs, tbl);
    wd_mix<<<7360, 256, 0, stream>>>(bufs, pred[0], pred[1], pred[2], pred[3],
                                     pred[4], pred[5], gt[0], gt[1], gt[2],
                                     (const float*)d_in[9], tbl, partials);
    fin_pre<<<NSLOTS, 64, 0, stream>>>(partials, ssum);
    finalize<<<1, 64, 0, stream>>>(ssum,
                                   (const float*)d_in[10], (const float*)d_in[11],
                                   (const float*)d_in[12], (const float*)d_in[13],
                                   (float*)d_out);
}